// Round 6
// baseline (86.206 us; speedup 1.0000x reference)
//
#include <hip/hip_runtime.h>

#define HW_   50176      // 224*224
#define QHW_  12544      // HW_/4
#define PSTR_ 196608     // 64*32*32*3 floats per image

typedef float f32x4u __attribute__((ext_vector_type(4), aligned(4)));
typedef float f32x2u __attribute__((ext_vector_type(2), aligned(4)));

__device__ __forceinline__ float fpow(float x, float e) {
    // x > 0 guaranteed by callers; v_log_f32 is log2, v_exp_f32 is exp2
    return __builtin_amdgcn_exp2f(e * __builtin_amdgcn_logf(x));
}

__device__ __forceinline__ float srgb_lin(float c) {
    return c < 0.04045f ? c * (1.0f / 12.92f)
                        : fpow((c + 0.055f) * (1.0f / 1.055f), 2.4f);
}

__device__ __forceinline__ float enc_srgb(float c) {
    float e = (c < 0.0031308f)
                  ? 12.92f * c
                  : 1.055f * fpow(fmaxf(c, 1e-10f), 1.0f / 2.4f) - 0.055f;
    return fminf(fmaxf(e, 0.0f), 1.0f);
}

__global__ __launch_bounds__(256) void cieluv_k6(
    const float* __restrict__ imgs,
    const float* __restrict__ params,
    float* __restrict__ out)
{
    // XCD-chunk swizzle (bijective: gridDim.x=3136 divisible by 8)
    int bid = blockIdx.x;
    int cpx = gridDim.x >> 3;                 // 392
    int b   = (bid & 7) * cpx + (bid >> 3);

    int vi = b * 256 + threadIdx.x;           // vector-of-4-pixels index
    int n  = vi / QHW_;                       // image
    int pv = (vi - n * QHW_) * 4;             // pixel offset within plane

    const float* img = imgs + (size_t)n * (3 * HW_) + pv;
    float4 rv = *(const float4*)(img);
    float4 gv = *(const float4*)(img + HW_);
    float4 bv = *(const float4*)(img + 2 * HW_);
    const float* __restrict__ plist = params + (size_t)n * PSTR_;

    float Rr[4] = {rv.x, rv.y, rv.z, rv.w};
    float Gg[4] = {gv.x, gv.y, gv.z, gv.w};
    float Bb[4] = {bv.x, bv.y, bv.z, bv.w};
    float O0[4], O1[4], O2[4];

#pragma unroll
    for (int i = 0; i < 4; ++i) {
        // ---- sRGB -> linear ----
        float r = srgb_lin(Rr[i]);
        float g = srgb_lin(Gg[i]);
        float bl = srgb_lin(Bb[i]);
        // ---- linear RGB -> XYZ ----
        float x = 0.4124f * r + 0.3576f * g + 0.1805f * bl;
        float y = 0.2126f * r + 0.7152f * g + 0.0722f * bl;
        float z = 0.0193f * r + 0.1192f * g + 0.9504f * bl;
        // ---- XYZ -> LUV (normalized) ----
        float inv = 1.0f / (x + 15.0f * y + 3.0f * z + 1e-10f);
        float up = 4.0f * x * inv;
        float vp = 9.0f * y * inv;
        float L = (y < 0.008856451679035631f)
                      ? 903.2962962962963f * y
                      : 116.0f * fpow(fmaxf(y, 1e-10f), 1.0f / 3.0f) - 16.0f;
        float u = 13.0f * L * (up - 0.1978f);
        float v = 13.0f * L * (vp - 0.4683f);
        float c0 = L * 0.01f;
        float c1 = (u + 100.0f) * 0.005f;
        float c2 = (v + 100.0f) * 0.005f;
        // ---- trilinear LUT (RX=64, RY=32, RZ=32) ----
        float s0 = c0 * 63.0f, s1 = c1 * 31.0f, s2 = c2 * 31.0f;
        float f0 = floorf(s0), f1 = floorf(s1), f2 = floorf(s2);
        float w1x = s0 - f0, w1y = s1 - f1, w1z = s2 - f2;   // == s % 1
        float w0x = 1.0f - w1x, w0y = 1.0f - w1y, w0z = 1.0f - w1z;
        int i0 = (int)f0, i1 = (int)f1, i2 = (int)f2;
        int ix0 = min(max(i0, 0), 63), ix1 = min(max(i0 + 1, 0), 63);
        int iy0 = min(max(i1, 0), 31), iy1 = min(max(i1 + 1, 0), 31);
        // z-pair base: corners (iz0, iz0+1) are 6 CONTIGUOUS floats.
        int izb = min(max(i2, 0), 30);
        // z-clamp folded into pair weights (exact: out-of-range z makes both
        // ref corners alias one entry, weights sum preserved):
        //   i2 in [0,30]: wlo=w0z, whi=w1z ; i2>=31: both->hi ; i2<0: both->lo
        float wlo = (i2 >= 31) ? 0.0f : ((i2 < 0) ? 1.0f : w0z);
        float whi = 1.0f - wlo - ((i2 >= 31) || (i2 < 0) ? 0.0f : 0.0f);
        whi = (i2 >= 31) ? 1.0f : ((i2 < 0) ? 0.0f : w1z);

        int e00 = ((ix0 << 10) + (iy0 << 5) + izb) * 3;
        int e01 = ((ix0 << 10) + (iy1 << 5) + izb) * 3;
        int e10 = ((ix1 << 10) + (iy0 << 5) + izb) * 3;
        int e11 = ((ix1 << 10) + (iy1 << 5) + izb) * 3;

        // ---- 4 pair-gathers, 2 VMEM ops each (dwordx4 + dwordx2) ----
        f32x4u A0 = *(const f32x4u*)(plist + e00);
        f32x2u B0 = *(const f32x2u*)(plist + e00 + 4);
        f32x4u A1 = *(const f32x4u*)(plist + e01);
        f32x2u B1 = *(const f32x2u*)(plist + e01 + 4);
        f32x4u A2 = *(const f32x4u*)(plist + e10);
        f32x2u B2 = *(const f32x2u*)(plist + e10 + 4);
        f32x4u A3 = *(const f32x4u*)(plist + e11);
        f32x2u B3 = *(const f32x2u*)(plist + e11 + 4);
        // layout: A = {lo.x, lo.y, lo.z, hi.x}, B = {hi.y, hi.z}

        float wxy00 = w0x * w0y;
        float wxy01 = w0x * w1y;
        float wxy10 = w1x * w0y;
        float wxy11 = w1x * w1y;

        float a0 = wxy00 * (A0.x * wlo + A0.w * whi)
                 + wxy01 * (A1.x * wlo + A1.w * whi)
                 + wxy10 * (A2.x * wlo + A2.w * whi)
                 + wxy11 * (A3.x * wlo + A3.w * whi);
        float a1 = wxy00 * (A0.y * wlo + B0.x * whi)
                 + wxy01 * (A1.y * wlo + B1.x * whi)
                 + wxy10 * (A2.y * wlo + B2.x * whi)
                 + wxy11 * (A3.y * wlo + B3.x * whi);
        float a2 = wxy00 * (A0.z * wlo + B0.y * whi)
                 + wxy01 * (A1.z * wlo + B1.y * whi)
                 + wxy10 * (A2.z * wlo + B2.y * whi)
                 + wxy11 * (A3.z * wlo + B3.y * whi);

        a0 = fminf(fmaxf(a0, 0.0f), 1.0f);
        a1 = fminf(fmaxf(a1, 0.0f), 1.0f);
        a2 = fminf(fmaxf(a2, 0.0f), 1.0f);
        // ---- LUV -> XYZ ----
        float L2 = a0 * 100.0f;
        float uu = a1 * 200.0f - 100.0f;
        float vv = a2 * 200.0f - 100.0f;
        float idl = 1.0f / (13.0f * L2 + 1e-10f);
        float up2 = uu * idl + 0.1978f;
        float vp2 = vv * idl + 0.4683f;
        float y2;
        if (L2 <= 8.0f) {
            y2 = L2 * 0.0011070564598794539f;       // (3/29)^3
        } else {
            float t = (L2 + 16.0f) * (1.0f / 116.0f);
            y2 = t * t * t;
        }
        float dn = 4.0f * vp2 + 1e-10f;
        float x2 = y2 * 9.0f * up2 / dn;
        float z2 = y2 * (12.0f - 3.0f * up2 - 20.0f * vp2) / dn;
        x2 = fminf(fmaxf(x2, 0.0f), 1.1f);
        float y2c = fminf(fmaxf(y2, 0.0f), 1.1f);
        z2 = fminf(fmaxf(z2, 0.0f), 1.1f);
        // ---- XYZ -> sRGB ----
        float rr = 3.2406f * x2 - 1.5372f * y2c - 0.4986f * z2;
        float gg = -0.9689f * x2 + 1.8758f * y2c + 0.0415f * z2;
        float b2 = 0.0557f * x2 - 0.2040f * y2c + 1.0570f * z2;
        O0[i] = enc_srgb(rr);
        O1[i] = enc_srgb(gg);
        O2[i] = enc_srgb(b2);
    }

    float* o = out + (size_t)n * (3 * HW_) + pv;
    *(float4*)(o)           = make_float4(O0[0], O0[1], O0[2], O0[3]);
    *(float4*)(o + HW_)     = make_float4(O1[0], O1[1], O1[2], O1[3]);
    *(float4*)(o + 2 * HW_) = make_float4(O2[0], O2[1], O2[2], O2[3]);
}

extern "C" void kernel_launch(void* const* d_in, const int* in_sizes, int n_in,
                              void* d_out, int out_size, void* d_ws, size_t ws_size,
                              hipStream_t stream) {
    const float* imgs   = (const float*)d_in[0];   // (64,3,224,224) f32
    const float* params = (const float*)d_in[1];   // (64,64,32,32,3) f32
    float* out = (float*)d_out;                    // (64,3,224,224) f32
    cieluv_k6<<<dim3(3136), dim3(256), 0, stream>>>(imgs, params, out);
}

// Round 8
// 64.168 us; speedup vs baseline: 1.3434x; 1.3434x over previous
//
#include <hip/hip_runtime.h>

#define HW_   50176      // 224*224
#define PSTR_ 196608     // 64*32*32*3 floats per image

__device__ __forceinline__ float fpow(float x, float e) {
    // x > 0 guaranteed by callers; v_log_f32 is log2, v_exp_f32 is exp2
    return __builtin_amdgcn_exp2f(e * __builtin_amdgcn_logf(x));
}

__device__ __forceinline__ float srgb_lin(float c) {
    return c < 0.04045f ? c * (1.0f / 12.92f)
                        : fpow((c + 0.055f) * (1.0f / 1.055f), 2.4f);
}

__device__ __forceinline__ float enc_srgb(float c) {
    float e = (c < 0.0031308f)
                  ? 12.92f * c
                  : 1.055f * fpow(fmaxf(c, 1e-10f), 1.0f / 2.4f) - 0.055f;
    return fminf(fmaxf(e, 0.0f), 1.0f);
}

__global__ __launch_bounds__(256) void cieluv_k8(
    const float* __restrict__ imgs,
    const float* __restrict__ params,
    float* __restrict__ out)
{
    // XCD-chunk swizzle (bijective: gridDim.x=12544 divisible by 8)
    int bid = blockIdx.x;
    int cpx = gridDim.x >> 3;                 // 1568
    int b   = (bid & 7) * cpx + (bid >> 3);

    int vi = b * 256 + threadIdx.x;           // pixel index (1 px/thread)
    int n  = vi / HW_;                        // image
    int pv = vi - n * HW_;                    // pixel offset within plane

    const float* img = imgs + (size_t)n * (3 * HW_) + pv;
    float rr_in = img[0];
    float gg_in = img[HW_];
    float bb_in = img[2 * HW_];
    const float* __restrict__ plist = params + (size_t)n * PSTR_;

    // ---- sRGB -> linear ----
    float r = srgb_lin(rr_in);
    float g = srgb_lin(gg_in);
    float bl = srgb_lin(bb_in);
    // ---- linear RGB -> XYZ ----
    float x = 0.4124f * r + 0.3576f * g + 0.1805f * bl;
    float y = 0.2126f * r + 0.7152f * g + 0.0722f * bl;
    float z = 0.0193f * r + 0.1192f * g + 0.9504f * bl;
    // ---- XYZ -> LUV (normalized) ----
    float inv = 1.0f / (x + 15.0f * y + 3.0f * z + 1e-10f);
    float up = 4.0f * x * inv;
    float vp = 9.0f * y * inv;
    float L = (y < 0.008856451679035631f)
                  ? 903.2962962962963f * y
                  : 116.0f * fpow(fmaxf(y, 1e-10f), 1.0f / 3.0f) - 16.0f;
    float u = 13.0f * L * (up - 0.1978f);
    float v = 13.0f * L * (vp - 0.4683f);
    float c0 = L * 0.01f;
    float c1 = (u + 100.0f) * 0.005f;
    float c2 = (v + 100.0f) * 0.005f;
    // ---- trilinear LUT (RX=64, RY=32, RZ=32) ----
    float s0 = c0 * 63.0f, s1 = c1 * 31.0f, s2 = c2 * 31.0f;
    float f0 = floorf(s0), f1 = floorf(s1), f2 = floorf(s2);
    float w1x = s0 - f0, w1y = s1 - f1, w1z = s2 - f2;   // == s % 1
    float w0x = 1.0f - w1x, w0y = 1.0f - w1y, w0z = 1.0f - w1z;
    int i0 = (int)f0, i1 = (int)f1, i2 = (int)f2;
    int ix0 = min(max(i0, 0), 63), ix1 = min(max(i0 + 1, 0), 63);
    int iy0 = min(max(i1, 0), 31), iy1 = min(max(i1 + 1, 0), 31);
    int iz0 = min(max(i2, 0), 31), iz1 = min(max(i2 + 1, 0), 31);
    int bx0 = ix0 << 10, bx1 = ix1 << 10;
    int by0 = iy0 << 5,  by1 = iy1 << 5;

    // ---- 8 corner gathers into named scalars ----
    const float* p0 = plist + (bx0 + by0 + iz0) * 3;
    const float* p1 = plist + (bx0 + by0 + iz1) * 3;
    const float* p2 = plist + (bx0 + by1 + iz0) * 3;
    const float* p3 = plist + (bx0 + by1 + iz1) * 3;
    const float* p4 = plist + (bx1 + by0 + iz0) * 3;
    const float* p5 = plist + (bx1 + by0 + iz1) * 3;
    const float* p6 = plist + (bx1 + by1 + iz0) * 3;
    const float* p7 = plist + (bx1 + by1 + iz1) * 3;
    float c0x = p0[0], c0y = p0[1], c0z = p0[2];
    float c1x = p1[0], c1y = p1[1], c1z = p1[2];
    float c2x = p2[0], c2y = p2[1], c2z = p2[2];
    float c3x = p3[0], c3y = p3[1], c3z = p3[2];
    float c4x = p4[0], c4y = p4[1], c4z = p4[2];
    float c5x = p5[0], c5y = p5[1], c5z = p5[2];
    float c6x = p6[0], c6y = p6[1], c6z = p6[2];
    float c7x = p7[0], c7y = p7[1], c7z = p7[2];

    float w000 = w0x * w0y * w0z;
    float w001 = w0x * w0y * w1z;
    float w010 = w0x * w1y * w0z;
    float w011 = w0x * w1y * w1z;
    float w100 = w1x * w0y * w0z;
    float w101 = w1x * w0y * w1z;
    float w110 = w1x * w1y * w0z;
    float w111 = w1x * w1y * w1z;

    float a0 = c0x * w000 + c1x * w001 + c2x * w010 + c3x * w011
             + c4x * w100 + c5x * w101 + c6x * w110 + c7x * w111;
    float a1 = c0y * w000 + c1y * w001 + c2y * w010 + c3y * w011
             + c4y * w100 + c5y * w101 + c6y * w110 + c7y * w111;
    float a2 = c0z * w000 + c1z * w001 + c2z * w010 + c3z * w011
             + c4z * w100 + c5z * w101 + c6z * w110 + c7z * w111;

    a0 = fminf(fmaxf(a0, 0.0f), 1.0f);
    a1 = fminf(fmaxf(a1, 0.0f), 1.0f);
    a2 = fminf(fmaxf(a2, 0.0f), 1.0f);
    // ---- LUV -> XYZ ----
    float L2 = a0 * 100.0f;
    float uu = a1 * 200.0f - 100.0f;
    float vv = a2 * 200.0f - 100.0f;
    float idl = 1.0f / (13.0f * L2 + 1e-10f);
    float up2 = uu * idl + 0.1978f;
    float vp2 = vv * idl + 0.4683f;
    float y2;
    if (L2 <= 8.0f) {
        y2 = L2 * 0.0011070564598794539f;       // (3/29)^3
    } else {
        float t = (L2 + 16.0f) * (1.0f / 116.0f);
        y2 = t * t * t;
    }
    float dn = 4.0f * vp2 + 1e-10f;
    float x2 = y2 * 9.0f * up2 / dn;
    float z2 = y2 * (12.0f - 3.0f * up2 - 20.0f * vp2) / dn;
    x2 = fminf(fmaxf(x2, 0.0f), 1.1f);
    float y2c = fminf(fmaxf(y2, 0.0f), 1.1f);
    z2 = fminf(fmaxf(z2, 0.0f), 1.1f);
    // ---- XYZ -> sRGB ----
    float rr = 3.2406f * x2 - 1.5372f * y2c - 0.4986f * z2;
    float gg = -0.9689f * x2 + 1.8758f * y2c + 0.0415f * z2;
    float b2 = 0.0557f * x2 - 0.2040f * y2c + 1.0570f * z2;

    float* o = out + (size_t)n * (3 * HW_) + pv;
    o[0]       = enc_srgb(rr);
    o[HW_]     = enc_srgb(gg);
    o[2 * HW_] = enc_srgb(b2);
}

extern "C" void kernel_launch(void* const* d_in, const int* in_sizes, int n_in,
                              void* d_out, int out_size, void* d_ws, size_t ws_size,
                              hipStream_t stream) {
    const float* imgs   = (const float*)d_in[0];   // (64,3,224,224) f32
    const float* params = (const float*)d_in[1];   // (64,64,32,32,3) f32
    float* out = (float*)d_out;                    // (64,3,224,224) f32
    // 64 images * 50176 px/image = 3211264 threads = 12544 blocks * 256
    cieluv_k8<<<dim3(12544), dim3(256), 0, stream>>>(imgs, params, out);
}